// Round 2
// baseline (52.845 us; speedup 1.0000x reference)
//
#include <hip/hip_runtime.h>

#define BB 2
#define NN 768
#define FIN 10

// workspace layout (float offsets)
#define WPQ_OFF 0                          // 128*128
#define S1P_OFF 16384                      // B*6*128
#define S2P_OFF (S1P_OFF + BB*6*128)       // B*12*128
#define H1_OFF  (S2P_OFF + BB*12*128)      // B*128*768
#define H2_OFF  (H1_OFF + BB*128*NN)       // B*128*768
#define PP_OFF  (H2_OFF + BB*128*NN)       // B*64*768
#define QQ_OFF  (PP_OFF + BB*64*NN)        // B*64*768

// ---------------- K0: Wpq[o][c] = sum_k S[o][k]*(w1_2[k][c]+w2_2[k][c]) ----------------
// o<64: S[o][k]=sw0[o][k] (p-half); o>=64: S[o][k]=sw0[o-64][64+k] (q-half)
// grid(8), block 256; block handles 16 o rows
__global__ void k_wpq(const float* __restrict__ sw0, const float* __restrict__ w1_2,
                      const float* __restrict__ w2_2, float* __restrict__ wpq)
{
    const int o0 = blockIdx.x * 16, tid = threadIdx.x;
    __shared__ float w2l[64][132];
    __shared__ float sl[16][64];
    for (int idx = tid; idx < 2048; idx += 256) {
        int k = idx >> 5, c4 = (idx & 31) * 4;
        float4 a = *(const float4*)&w1_2[k * 128 + c4];
        float4 b = *(const float4*)&w2_2[k * 128 + c4];
        float4 r = {a.x + b.x, a.y + b.y, a.z + b.z, a.w + b.w};
        *(float4*)&w2l[k][c4] = r;
    }
    for (int idx = tid; idx < 16 * 64; idx += 256) {
        int o = idx >> 6, k = idx & 63;
        int oo = o0 + o;
        sl[o][k] = (oo < 64) ? sw0[oo * 128 + k] : sw0[(oo - 64) * 128 + 64 + k];
    }
    __syncthreads();
    const int tx = tid & 31, ty = tid >> 5;   // ty 0..7, 2 o rows each
    float4 a0 = {0, 0, 0, 0}, a1 = {0, 0, 0, 0};
    for (int k = 0; k < 64; ++k) {
        float4 wv = *(const float4*)&w2l[k][tx * 4];
        float s0 = sl[ty * 2][k], s1 = sl[ty * 2 + 1][k];
        a0.x += s0 * wv.x; a0.y += s0 * wv.y; a0.z += s0 * wv.z; a0.w += s0 * wv.w;
        a1.x += s1 * wv.x; a1.y += s1 * wv.y; a1.z += s1 * wv.z; a1.w += s1 * wv.w;
    }
    *(float4*)&wpq[(o0 + ty * 2) * 128 + tx * 4] = a0;
    *(float4*)&wpq[(o0 + ty * 2 + 1) * 128 + tx * 4] = a1;
}

// ---------------- K1: layer0 (mean computed in-block), h1 + partial colsums ----------------
// grid (B, 6), block 256; n-tile 128, all 128 o
__global__ void k_layer0(const float* __restrict__ x, const float* __restrict__ w1,
                         const float* __restrict__ w2, const float* __restrict__ b1,
                         const float* __restrict__ b2, float* __restrict__ h1,
                         float* __restrict__ s1p)
{
    const int b = blockIdx.x, nblk = blockIdx.y, n0 = nblk * 128, tid = threadIdx.x;
    __shared__ float red[FIN][257];
    __shared__ float mu[FIN];
    __shared__ float xt[FIN][128];
    __shared__ float wl[FIN][128];
    __shared__ float offs[128];
    __shared__ float red2[8][16][33];
    float acc[FIN];
#pragma unroll
    for (int c = 0; c < FIN; ++c) acc[c] = 0.f;
    for (int n = tid; n < NN; n += 256) {
        const float* xp = x + (b * NN + n) * FIN;
#pragma unroll
        for (int c = 0; c < FIN; ++c) acc[c] += xp[c];
    }
#pragma unroll
    for (int c = 0; c < FIN; ++c) red[c][tid] = acc[c];
    __syncthreads();
    for (int s = 128; s > 0; s >>= 1) {
        if (tid < s) {
#pragma unroll
            for (int c = 0; c < FIN; ++c) red[c][tid] += red[c][tid + s];
        }
        __syncthreads();
    }
    if (tid < FIN) mu[tid] = red[tid][0] * (1.f / (float)NN);
    for (int idx = tid; idx < FIN * 128; idx += 256) {
        int n = idx / FIN, c = idx % FIN;
        xt[c][n] = x[(b * NN + n0 + n) * FIN + c];
    }
    for (int idx = tid; idx < FIN * 128; idx += 256) {
        int o = idx / FIN, c = idx % FIN;
        wl[c][o] = w1[o * FIN + c] + w2[o * FIN + c];
    }
    __syncthreads();
    if (tid < 128) {
        float o = b1[tid] + b2[tid];
#pragma unroll
        for (int c = 0; c < FIN; ++c) o -= w2[tid * FIN + c] * mu[c];
        offs[tid] = o;
    }
    __syncthreads();
    const int tx = tid & 31, ty = tid >> 5;
    float4 av[16];
#pragma unroll
    for (int a = 0; a < 16; ++a) {
        float o = offs[ty * 16 + a];
        av[a] = make_float4(o, o, o, o);
    }
#pragma unroll
    for (int c = 0; c < FIN; ++c) {
        float4 xv = *(const float4*)&xt[c][tx * 4];
#pragma unroll
        for (int a = 0; a < 16; ++a) {
            float w = wl[c][ty * 16 + a];
            av[a].x += w * xv.x; av[a].y += w * xv.y;
            av[a].z += w * xv.z; av[a].w += w * xv.w;
        }
    }
#pragma unroll
    for (int a = 0; a < 16; ++a) {
        float4 r = av[a];
        r.x = fmaxf(r.x, 0.f); r.y = fmaxf(r.y, 0.f);
        r.z = fmaxf(r.z, 0.f); r.w = fmaxf(r.w, 0.f);
        *(float4*)&h1[((size_t)(b * 128 + ty * 16 + a)) * NN + n0 + tx * 4] = r;
        red2[ty][a][tx] = r.x + r.y + r.z + r.w;
    }
    __syncthreads();
    if (tid < 128) {
        float s = 0.f;
#pragma unroll
        for (int t = 0; t < 32; ++t) s += red2[tid >> 4][tid & 15][t];
        s1p[(b * 6 + nblk) * 128 + tid] = s;
    }
}

// ---------------- K2: layer1, h2 + partial colsums ----------------
// grid (B, 12, 2), block 256; n-tile 64, o-tile 64
__global__ void k_layer1(const float* __restrict__ h1, const float* __restrict__ w1,
                         const float* __restrict__ b1, const float* __restrict__ w2,
                         const float* __restrict__ b2, const float* __restrict__ s1p,
                         float* __restrict__ h2, float* __restrict__ s2p)
{
    const int b = blockIdx.x, nblk = blockIdx.y, n0 = nblk * 64,
              o0 = blockIdx.z * 64, tid = threadIdx.x;
    __shared__ float hl[128][64];
    __shared__ float wl[64][132];
    __shared__ float mul[128];
    __shared__ float offp[4][64];
    __shared__ float offs[64];
    __shared__ float red[16][4][17];
    if (tid < 128) {
        float s = 0.f;
#pragma unroll
        for (int k = 0; k < 6; ++k) s += s1p[(b * 6 + k) * 128 + tid];
        mul[tid] = s * (1.f / (float)NN);
    }
    for (int idx = tid; idx < 2048; idx += 256) {
        int c = idx >> 4, n4 = (idx & 15) * 4;
        *(float4*)&hl[c][n4] = *(const float4*)&h1[((size_t)(b * 128 + c)) * NN + n0 + n4];
    }
    for (int idx = tid; idx < 2048; idx += 256) {
        int o = idx >> 5, c4 = (idx & 31) * 4;
        float4 a = *(const float4*)&w1[(o0 + o) * 128 + c4];
        float4 bb = *(const float4*)&w2[(o0 + o) * 128 + c4];
        float4 r = {a.x + bb.x, a.y + bb.y, a.z + bb.z, a.w + bb.w};
        *(float4*)&wl[o][c4] = r;
    }
    __syncthreads();
    {
        int o = tid & 63, part = tid >> 6;
        const float* w2r = w2 + (o0 + o) * 128 + part * 32;
        const float* mr = mul + part * 32;
        float p = 0.f;
#pragma unroll
        for (int i = 0; i < 32; ++i) p += w2r[i] * mr[i];
        offp[part][o] = p;
    }
    __syncthreads();
    if (tid < 64)
        offs[tid] = b1[o0 + tid] + b2[o0 + tid]
                  - offp[0][tid] - offp[1][tid] - offp[2][tid] - offp[3][tid];
    __syncthreads();
    const int tx = tid & 15, ty = tid >> 4;
    float4 acc[4];
#pragma unroll
    for (int a = 0; a < 4; ++a) acc[a] = make_float4(0.f, 0.f, 0.f, 0.f);
    for (int c = 0; c < 128; ++c) {
        float4 hv = *(const float4*)&hl[c][tx * 4];
#pragma unroll
        for (int a = 0; a < 4; ++a) {
            float w = wl[ty * 4 + a][c];
            acc[a].x += w * hv.x; acc[a].y += w * hv.y;
            acc[a].z += w * hv.z; acc[a].w += w * hv.w;
        }
    }
#pragma unroll
    for (int a = 0; a < 4; ++a) {
        int o = ty * 4 + a;
        float off = offs[o];
        float4 r = acc[a];
        r.x = fmaxf(r.x + off, 0.f); r.y = fmaxf(r.y + off, 0.f);
        r.z = fmaxf(r.z + off, 0.f); r.w = fmaxf(r.w + off, 0.f);
        *(float4*)&h2[((size_t)(b * 128 + o0 + o)) * NN + n0 + tx * 4] = r;
        red[ty][a][tx] = r.x + r.y + r.z + r.w;
    }
    __syncthreads();
    if (tid < 64) {
        float s = 0.f;
#pragma unroll
        for (int t = 0; t < 16; ++t) s += red[tid >> 2][tid & 3][t];
        s2p[(b * 12 + nblk) * 128 + o0 + tid] = s;
    }
}

// ---------------- K3: pp/qq = Wpq @ h2 + bias (layer2 & sw0 folded) ----------------
// grid (B, 12, 2), block 256; z=0 -> pp rows (0..63 of wpq), z=1 -> qq rows (64..127)
__global__ void k_pq(const float* __restrict__ h2, const float* __restrict__ wpq,
                     const float* __restrict__ b1_2, const float* __restrict__ w2_2,
                     const float* __restrict__ b2_2, const float* __restrict__ sw0,
                     const float* __restrict__ sb0, const float* __restrict__ s2p,
                     float* __restrict__ pp, float* __restrict__ qq)
{
    const int b = blockIdx.x, nblk = blockIdx.y, n0 = nblk * 64,
              z = blockIdx.z, o0 = z * 64, tid = threadIdx.x;
    __shared__ float hl[128][64];
    __shared__ float wl[64][132];
    __shared__ float mul[128];
    __shared__ float offp[4][64];
    __shared__ float off2[64];
    __shared__ float bp[4][64];
    __shared__ float bias[64];
    if (tid < 128) {
        float s = 0.f;
#pragma unroll
        for (int k = 0; k < 12; ++k) s += s2p[(b * 12 + k) * 128 + tid];
        mul[tid] = s * (1.f / (float)NN);
    }
    for (int idx = tid; idx < 2048; idx += 256) {
        int c = idx >> 4, n4 = (idx & 15) * 4;
        *(float4*)&hl[c][n4] = *(const float4*)&h2[((size_t)(b * 128 + c)) * NN + n0 + n4];
    }
    for (int idx = tid; idx < 2048; idx += 256) {
        int o = idx >> 5, c4 = (idx & 31) * 4;
        *(float4*)&wl[o][c4] = *(const float4*)&wpq[(o0 + o) * 128 + c4];
    }
    __syncthreads();
    {   // off2[k] for u-channels k=0..63: b1_2+b2_2 - w2_2 @ mul
        int k = tid & 63, part = tid >> 6;
        const float* w2r = w2_2 + k * 128 + part * 32;
        const float* mr = mul + part * 32;
        float p = 0.f;
#pragma unroll
        for (int i = 0; i < 32; ++i) p += w2r[i] * mr[i];
        offp[part][k] = p;
    }
    __syncthreads();
    if (tid < 64)
        off2[tid] = b1_2[tid] + b2_2[tid]
                  - offp[0][tid] - offp[1][tid] - offp[2][tid] - offp[3][tid];
    __syncthreads();
    {   // bias[o] = sum_k S[o][k]*off2[k]  (+ sb0[o] for the p half)
        int o = tid & 63, part = tid >> 6;
        const float* srow = sw0 + o * 128 + (z ? 64 : 0) + part * 16;
        float p = 0.f;
#pragma unroll
        for (int i = 0; i < 16; ++i) p += srow[i] * off2[part * 16 + i];
        bp[part][o] = p;
    }
    __syncthreads();
    if (tid < 64)
        bias[tid] = bp[0][tid] + bp[1][tid] + bp[2][tid] + bp[3][tid]
                  + (z == 0 ? sb0[tid] : 0.f);
    __syncthreads();
    const int tx = tid & 15, ty = tid >> 4;
    float4 acc[4];
#pragma unroll
    for (int a = 0; a < 4; ++a) acc[a] = make_float4(0.f, 0.f, 0.f, 0.f);
    for (int c = 0; c < 128; ++c) {
        float4 hv = *(const float4*)&hl[c][tx * 4];
#pragma unroll
        for (int a = 0; a < 4; ++a) {
            float w = wl[ty * 4 + a][c];
            acc[a].x += w * hv.x; acc[a].y += w * hv.y;
            acc[a].z += w * hv.z; acc[a].w += w * hv.w;
        }
    }
    float* dst = (z == 0) ? pp : qq;
#pragma unroll
    for (int a = 0; a < 4; ++a) {
        int o = ty * 4 + a;
        float bb = bias[o];
        float4 r = acc[a];
        r.x += bb; r.y += bb; r.z += bb; r.w += bb;
        *(float4*)&dst[((size_t)(b * 64 + o)) * NN + n0 + tx * 4] = r;
    }
}

// ---------------- K4: out[b,i,j] = sb1 + sum_c sw1[c]*relu(pp[c,j]+qq[c,i]) ----------------
// grid (B, 12, 12), block 512; 64x64 output tile, 2i x 4j per thread
__global__ void k_final(const float* __restrict__ pp, const float* __restrict__ qq,
                        const float* __restrict__ sw1, const float* __restrict__ sb1,
                        float* __restrict__ out)
{
    const int b = blockIdx.x, i0 = blockIdx.y * 64, j0 = blockIdx.z * 64, tid = threadIdx.x;
    __shared__ float pl[64][64];
    __shared__ float ql[64][64];
    __shared__ float wl[64];
    __shared__ float sbv;
    for (int idx = tid; idx < 4096; idx += 512) {
        int c = idx >> 6, k = idx & 63;
        pl[c][k] = pp[((size_t)(b * 64 + c)) * NN + j0 + k];
        ql[c][k] = qq[((size_t)(b * 64 + c)) * NN + i0 + k];
    }
    if (tid < 64) wl[tid] = sw1[tid];
    if (tid == 0) sbv = sb1[0];
    __syncthreads();
    const int tx = tid & 15, ty = tid >> 4;  // tx: j/4 (0..15), ty: i/2 (0..31)
    float sb = sbv;
    float4 acc0 = {sb, sb, sb, sb}, acc1 = {sb, sb, sb, sb};
#pragma unroll 8
    for (int c = 0; c < 64; ++c) {
        float4 pv = *(const float4*)&pl[c][tx * 4];
        float q0 = ql[c][ty * 2], q1 = ql[c][ty * 2 + 1];
        float w = wl[c];
        acc0.x += w * fmaxf(pv.x + q0, 0.f);
        acc0.y += w * fmaxf(pv.y + q0, 0.f);
        acc0.z += w * fmaxf(pv.z + q0, 0.f);
        acc0.w += w * fmaxf(pv.w + q0, 0.f);
        acc1.x += w * fmaxf(pv.x + q1, 0.f);
        acc1.y += w * fmaxf(pv.y + q1, 0.f);
        acc1.z += w * fmaxf(pv.z + q1, 0.f);
        acc1.w += w * fmaxf(pv.w + q1, 0.f);
    }
    size_t base = (size_t)b * NN * NN + (size_t)(i0 + ty * 2) * NN + j0 + tx * 4;
    *(float4*)&out[base] = acc0;
    *(float4*)&out[base + NN] = acc1;
}

extern "C" void kernel_launch(void* const* d_in, const int* in_sizes, int n_in,
                              void* d_out, int out_size, void* d_ws, size_t ws_size,
                              hipStream_t stream)
{
    const float* x    = (const float*)d_in[0];
    const float* w1_0 = (const float*)d_in[1];
    const float* b1_0 = (const float*)d_in[2];
    const float* w2_0 = (const float*)d_in[3];
    const float* b2_0 = (const float*)d_in[4];
    const float* w1_1 = (const float*)d_in[5];
    const float* b1_1 = (const float*)d_in[6];
    const float* w2_1 = (const float*)d_in[7];
    const float* b2_1 = (const float*)d_in[8];
    const float* w1_2 = (const float*)d_in[9];
    const float* b1_2 = (const float*)d_in[10];
    const float* w2_2 = (const float*)d_in[11];
    const float* b2_2 = (const float*)d_in[12];
    const float* sw0  = (const float*)d_in[13];
    const float* sb0  = (const float*)d_in[14];
    const float* sw1  = (const float*)d_in[15];
    const float* sb1  = (const float*)d_in[16];

    float* ws   = (float*)d_ws;
    float* wpq  = ws + WPQ_OFF;
    float* s1p  = ws + S1P_OFF;
    float* s2p  = ws + S2P_OFF;
    float* h1   = ws + H1_OFF;
    float* h2   = ws + H2_OFF;
    float* pp   = ws + PP_OFF;
    float* qq   = ws + QQ_OFF;

    k_wpq   <<<8, 256, 0, stream>>>(sw0, w1_2, w2_2, wpq);
    k_layer0<<<dim3(BB, 6), 256, 0, stream>>>(x, w1_0, w2_0, b1_0, b2_0, h1, s1p);
    k_layer1<<<dim3(BB, 12, 2), 256, 0, stream>>>(h1, w1_1, b1_1, w2_1, b2_1, s1p, h2, s2p);
    k_pq    <<<dim3(BB, 12, 2), 256, 0, stream>>>(h2, wpq, b1_2, w2_2, b2_2, sw0, sb0, s2p, pp, qq);
    k_final <<<dim3(BB, 12, 12), 512, 0, stream>>>(pp, qq, sw1, sb1, (float*)d_out);
}